// Round 1
// baseline (567.865 us; speedup 1.0000x reference)
//
#include <hip/hip_runtime.h>

// MultiEdgeTypePredictor fused kernel (fp32 baseline).
//
// Per 64-edge tile (one 256-thread block):
//   GEMM1: x[64][128] = relu(concat(hsrc,hdst)[64][512] @ W1 + b1), then
//          BN(running stats) + emb[etype]  -- K staged in 64-chunks in LDS
//   GEMM2: y[64][64] = relu(x @ W2 + b2)
//   GEMM3: out[e] = y[e] . W3 + b3

constexpr int IN_FEAT_C = 256;
constexpr int HID       = 128;
constexpr int H2        = 64;
constexpr int ETILE     = 64;
constexpr int KC        = 64;             // K-chunk for GEMM1
constexpr int NCHUNK    = 512 / KC;       // 8
constexpr int FSTRIDE   = KC + 4;         // 68  (pad: breaks pow2 bank stride)
constexpr int WSTRIDE   = HID + 4;        // 132 (pad, 16B-aligned rows)

__global__ __launch_bounds__(256)
void edge_mlp(const float* __restrict__ h_src, const float* __restrict__ h_dst,
              const int* __restrict__ src_nodes, const int* __restrict__ dst_nodes,
              const int* __restrict__ etype_idx,
              const float* __restrict__ W1, const float* __restrict__ b1,
              const float* __restrict__ bn_gamma, const float* __restrict__ bn_beta,
              const float* __restrict__ bn_mean, const float* __restrict__ bn_var,
              const float* __restrict__ emb,
              const float* __restrict__ W2, const float* __restrict__ b2,
              const float* __restrict__ W3, const float* __restrict__ b3,
              float* __restrict__ out, int n_edges)
{
    __shared__ alignas(16) float s_feat[ETILE * FSTRIDE];  // 17408 B; later: ytile[64][68]
    __shared__ alignas(16) float s_w[KC * WSTRIDE];        // 33792 B; later: xtile[64][132]
    __shared__ int s_src[ETILE];
    __shared__ int s_dst[ETILE];

    const int t     = threadIdx.x;
    const int ebase = blockIdx.x * ETILE;

    // preload gather indices (clamped for tail tile; stores are guarded later)
    if (t < ETILE) {
        int e = ebase + t;
        s_src[t] = src_nodes[e < n_edges ? e : 0];
    } else if (t < 2 * ETILE) {
        int e = ebase + (t - ETILE);
        s_dst[t - ETILE] = dst_nodes[e < n_edges ? e : 0];
    }

    const int cg = t & 15;   // 16 col-groups of 8 (GEMM1) / of 4 (GEMM2)
    const int eg = t >> 4;   // 16 edge-groups of 4

    float acc[4][8];
#pragma unroll
    for (int i = 0; i < 4; ++i)
#pragma unroll
        for (int j = 0; j < 8; ++j) acc[i][j] = 0.0f;

    // ---------------- GEMM1: K loop over 8 chunks of 64 ----------------
    for (int kc = 0; kc < NCHUNK; ++kc) {
        const int kbase = kc * KC;
        const float* hp   = (kbase < IN_FEAT_C) ? h_src : h_dst;
        const int*   sidx = (kbase < IN_FEAT_C) ? s_src : s_dst;
        const int    koff = kbase & (IN_FEAT_C - 1);

        __syncthreads();  // previous chunk's readers done (also covers idx preload)

        // stage features: 64 edges x 64 k = 1024 float4, 4 per thread
#pragma unroll
        for (int i = 0; i < 4; ++i) {
            int f = t + i * 256;
            int e = f >> 4;       // 16 float4 per edge-row
            int q = f & 15;
            int node = sidx[e];
            float4 v = *reinterpret_cast<const float4*>(
                hp + (size_t)node * IN_FEAT_C + koff + q * 4);
            *reinterpret_cast<float4*>(&s_feat[e * FSTRIDE + q * 4]) = v;
        }
        // stage W1 chunk: 64 rows x 128 cols = 2048 float4, 8 per thread
#pragma unroll
        for (int i = 0; i < 8; ++i) {
            int f = t + i * 256;
            int r = f >> 5;       // 32 float4 per row
            int q = f & 31;
            float4 v = *reinterpret_cast<const float4*>(
                W1 + (size_t)(kbase + r) * HID + q * 4);
            *reinterpret_cast<float4*>(&s_w[r * WSTRIDE + q * 4]) = v;
        }
        __syncthreads();

#pragma unroll 4
        for (int k = 0; k < KC; ++k) {
            float a[4];
#pragma unroll
            for (int i = 0; i < 4; ++i)
                a[i] = s_feat[(eg * 4 + i) * FSTRIDE + k];
            float4 w0 = *reinterpret_cast<const float4*>(&s_w[k * WSTRIDE + cg * 8]);
            float4 w1 = *reinterpret_cast<const float4*>(&s_w[k * WSTRIDE + cg * 8 + 4]);
            float wv[8] = {w0.x, w0.y, w0.z, w0.w, w1.x, w1.y, w1.z, w1.w};
#pragma unroll
            for (int i = 0; i < 4; ++i)
#pragma unroll
                for (int j = 0; j < 8; ++j)
                    acc[i][j] = fmaf(a[i], wv[j], acc[i][j]);
        }
    }

    // ------------- epilogue 1: bias + relu + BN + emb -> xtile -------------
    const int et = etype_idx[0];
    float xv[4][8];
#pragma unroll
    for (int j = 0; j < 8; ++j) {
        int c = cg * 8 + j;
        float sc = bn_gamma[c] * rsqrtf(bn_var[c] + 1e-5f);
        float sh = bn_beta[c] - bn_mean[c] * sc + emb[et * HID + c];
        float bb = b1[c];
#pragma unroll
        for (int i = 0; i < 4; ++i) {
            float x = fmaxf(acc[i][j] + bb, 0.0f);
            xv[i][j] = fmaf(x, sc, sh);
        }
    }

    __syncthreads();  // all GEMM1 reads of s_w done before aliasing as xtile
#pragma unroll
    for (int i = 0; i < 4; ++i)
#pragma unroll
        for (int j = 0; j < 8; ++j)
            s_w[(eg * 4 + i) * WSTRIDE + cg * 8 + j] = xv[i][j];
    __syncthreads();

    // ---------------- GEMM2: y[64][64] = relu(x @ W2 + b2) ----------------
    float acc2[4][4];
#pragma unroll
    for (int i = 0; i < 4; ++i)
#pragma unroll
        for (int j = 0; j < 4; ++j) acc2[i][j] = 0.0f;

#pragma unroll 4
    for (int k = 0; k < HID; ++k) {
        float a[4];
#pragma unroll
        for (int i = 0; i < 4; ++i)
            a[i] = s_w[(eg * 4 + i) * WSTRIDE + k];
        float4 w = *reinterpret_cast<const float4*>(W2 + (size_t)k * H2 + cg * 4);
        float wv[4] = {w.x, w.y, w.z, w.w};
#pragma unroll
        for (int i = 0; i < 4; ++i)
#pragma unroll
            for (int j = 0; j < 4; ++j)
                acc2[i][j] = fmaf(a[i], wv[j], acc2[i][j]);
    }

    // epilogue 2 -> ytile in s_feat (s_feat reads finished before xtile barrier)
#pragma unroll
    for (int j = 0; j < 4; ++j) {
        int c = cg * 4 + j;
        float bb = b2[c];
#pragma unroll
        for (int i = 0; i < 4; ++i) {
            float y = fmaxf(acc2[i][j] + bb, 0.0f);
            s_feat[(eg * 4 + i) * FSTRIDE + c] = y;
        }
    }
    __syncthreads();

    // ---------------- GEMM3: out[e] = y[e] . W3 + b3 ----------------
    {
        int e    = t >> 2;   // 0..63
        int part = t & 3;    // 4 lanes per edge
        float sum = 0.0f;
#pragma unroll
        for (int k = 0; k < 16; ++k) {
            int kk = part * 16 + k;
            sum = fmaf(s_feat[e * FSTRIDE + kk], W3[kk], sum);
        }
        sum += __shfl_xor(sum, 1);
        sum += __shfl_xor(sum, 2);
        if (part == 0 && ebase + e < n_edges)
            out[ebase + e] = sum + b3[0];
    }
}

extern "C" void kernel_launch(void* const* d_in, const int* in_sizes, int n_in,
                              void* d_out, int out_size, void* d_ws, size_t ws_size,
                              hipStream_t stream) {
    const float* h_src     = (const float*)d_in[0];
    const float* h_dst     = (const float*)d_in[1];
    const int*   src_nodes = (const int*)d_in[2];
    const int*   dst_nodes = (const int*)d_in[3];
    const int*   etype     = (const int*)d_in[4];
    const float* W1        = (const float*)d_in[5];
    const float* b1        = (const float*)d_in[6];
    const float* bn_gamma  = (const float*)d_in[7];
    const float* bn_beta   = (const float*)d_in[8];
    const float* bn_mean   = (const float*)d_in[9];
    const float* bn_var    = (const float*)d_in[10];
    const float* emb       = (const float*)d_in[11];
    const float* W2        = (const float*)d_in[12];
    const float* b2        = (const float*)d_in[13];
    const float* W3        = (const float*)d_in[14];
    const float* b3        = (const float*)d_in[15];

    const int n_edges = in_sizes[2];
    const int grid = (n_edges + ETILE - 1) / ETILE;

    edge_mlp<<<grid, 256, 0, stream>>>(h_src, h_dst, src_nodes, dst_nodes, etype,
                                       W1, b1, bn_gamma, bn_beta, bn_mean, bn_var,
                                       emb, W2, b2, W3, b3,
                                       (float*)d_out, n_edges);
}

// Round 2
// 103.551 us; speedup vs baseline: 5.4839x; 5.4839x over previous
//
#include <hip/hip_runtime.h>
#include <hip/hip_bf16.h>

// MultiEdgeTypePredictor — bf16 MFMA version.
//
// prep_kernel:  pack W1 (512x128) and W2 (128x64) into per-lane MFMA
//               B-fragment layout (bf16) in d_ws; fold BN+emb into sc/sh.
// edge_mlp_mfma: per 64-edge tile (256 thr = 4 waves):
//   GEMM1  x[64][128] = relu(feat[64][512] @ W1 + b1)*sc + sh   (MFMA 16x16x32)
//   GEMM2  y[64][64]  = relu(x @ W2 + b2)                       (MFMA 16x16x32)
//   GEMM3  out[e]     = y[e] . W3 + b3                          (fp32 + shfl)

typedef __attribute__((ext_vector_type(8))) short bf16x8;
typedef __attribute__((ext_vector_type(4))) float f32x4;

constexpr int HID   = 128;
constexpr int ETILE = 64;
constexpr int AS    = 136;   // LDS row stride in bf16 elems (272 B: 2-way max conflicts)

__device__ inline ushort f2bf(float f) {
    union { __hip_bfloat16 h; ushort u; } cv;
    cv.h = __float2bfloat16(f);   // RNE
    return cv.u;
}

// ---------------- prep: pack weights + fold BN/emb ----------------
__global__ __launch_bounds__(256)
void prep_kernel(const float* __restrict__ W1, const float* __restrict__ W2,
                 const float* __restrict__ bn_gamma, const float* __restrict__ bn_beta,
                 const float* __restrict__ bn_mean, const float* __restrict__ bn_var,
                 const float* __restrict__ emb, const int* __restrict__ etype,
                 ushort* __restrict__ B1p, ushort* __restrict__ B2p,
                 float* __restrict__ sc, float* __restrict__ sh)
{
    int i = blockIdx.x * blockDim.x + threadIdx.x;
    if (i < 65536) {
        // B1 frag: i = ((ks*8 + ct)*64 + lane)*8 + j ; k = ks*32+(lane>>4)*8+j ; c = ct*16+(lane&15)
        int j = i & 7, lane = (i >> 3) & 63, ct = (i >> 9) & 7, ks = i >> 12;
        int k = ks * 32 + (lane >> 4) * 8 + j;
        int c = ct * 16 + (lane & 15);
        B1p[i] = f2bf(W1[k * HID + c]);
    } else if (i < 65536 + 8192) {
        int p = i - 65536;
        int j = p & 7, lane = (p >> 3) & 63, ct = (p >> 9) & 3, ks = p >> 11;
        int k = ks * 32 + (lane >> 4) * 8 + j;
        int c = ct * 16 + (lane & 15);
        B2p[p] = f2bf(W2[k * 64 + c]);
    } else if (i < 65536 + 8192 + HID) {
        int c = i - 65536 - 8192;
        float s = bn_gamma[c] * rsqrtf(bn_var[c] + 1e-5f);
        sc[c] = s;
        sh[c] = bn_beta[c] - bn_mean[c] * s + emb[etype[0] * HID + c];
    }
}

// ---------------- main fused kernel ----------------
__global__ __launch_bounds__(256)
void edge_mlp_mfma(const float* __restrict__ h_src, const float* __restrict__ h_dst,
                   const int* __restrict__ src_nodes, const int* __restrict__ dst_nodes,
                   const ushort* __restrict__ B1p, const ushort* __restrict__ B2p,
                   const float* __restrict__ b1, const float* __restrict__ sc,
                   const float* __restrict__ sh, const float* __restrict__ b2,
                   const float* __restrict__ W3, const float* __restrict__ b3,
                   float* __restrict__ out, int n_edges)
{
    __shared__ ushort sA[ETILE * AS];          // 17408 B ; feat chunk, then x-tile
    __shared__ int s_src[ETILE], s_dst[ETILE];

    const int t    = threadIdx.x;
    const int lane = t & 63;
    const int w    = t >> 6;           // wave 0..3
    const int lr   = lane & 15;        // row-in-tile (A) / col (B,C)
    const int lq   = lane >> 4;        // quarter
    const int ebase = blockIdx.x * ETILE;

    if (t < ETILE) {
        int e = ebase + t;
        s_src[t] = src_nodes[e < n_edges ? e : 0];
    } else if (t < 2 * ETILE) {
        int e = ebase + t - ETILE;
        s_dst[t - ETILE] = dst_nodes[e < n_edges ? e : 0];
    }

    f32x4 acc[4][2];
#pragma unroll
    for (int rt = 0; rt < 4; ++rt)
#pragma unroll
        for (int c = 0; c < 2; ++c) acc[rt][c] = (f32x4)0.0f;

    // -------- GEMM1: 4 K-chunks of 128 (src lo/hi, dst lo/hi) --------
    for (int kc = 0; kc < 4; ++kc) {
        const float* hp   = (kc < 2) ? h_src : h_dst;
        const int*   sidx = (kc < 2) ? s_src : s_dst;
        const int    koff = (kc & 1) * 128;

        __syncthreads();   // previous chunk readers done (covers idx preload too)

        // stage 64 edges x 128 feats: 2048 float4, 8 per thread, fp32 -> bf16
#pragma unroll
        for (int i = 0; i < 8; ++i) {
            int f = t + i * 256;
            int e = f >> 5, q = f & 31;
            const float4 v = *reinterpret_cast<const float4*>(
                hp + (size_t)sidx[e] * 256 + koff + q * 4);
            ushort4 b;
            b.x = f2bf(v.x); b.y = f2bf(v.y); b.z = f2bf(v.z); b.w = f2bf(v.w);
            *reinterpret_cast<ushort4*>(&sA[e * AS + q * 4]) = b;
        }
        __syncthreads();

#pragma unroll
        for (int ks = 0; ks < 4; ++ks) {
            const int kstep = kc * 4 + ks;
            // wave w owns col-tiles {2w, 2w+1}; B frags from global (L2-hot)
            bf16x8 bf0 = *reinterpret_cast<const bf16x8*>(
                B1p + (size_t)(((kstep * 8) + 2 * w) * 64 + lane) * 8);
            bf16x8 bf1 = *reinterpret_cast<const bf16x8*>(
                B1p + (size_t)(((kstep * 8) + 2 * w + 1) * 64 + lane) * 8);
#pragma unroll
            for (int rt = 0; rt < 4; ++rt) {
                bf16x8 af = *reinterpret_cast<const bf16x8*>(
                    &sA[(rt * 16 + lr) * AS + ks * 32 + lq * 8]);
                acc[rt][0] = __builtin_amdgcn_mfma_f32_16x16x32_bf16(af, bf0, acc[rt][0], 0, 0, 0);
                acc[rt][1] = __builtin_amdgcn_mfma_f32_16x16x32_bf16(af, bf1, acc[rt][1], 0, 0, 0);
            }
        }
    }

    // -------- epilogue1: bias+relu+BN+emb -> x-tile (bf16, reuse sA) --------
    __syncthreads();   // all GEMM1 A-reads done before overwrite
#pragma unroll
    for (int ctl = 0; ctl < 2; ++ctl) {
        int c = (2 * w + ctl) * 16 + lr;
        float bb = b1[c], s = sc[c], z = sh[c];
#pragma unroll
        for (int rt = 0; rt < 4; ++rt)
#pragma unroll
            for (int r = 0; r < 4; ++r) {
                float x = fmaxf(acc[rt][ctl][r] + bb, 0.0f);
                sA[(rt * 16 + lq * 4 + r) * AS + c] = f2bf(fmaf(x, s, z));
            }
    }
    __syncthreads();

    // -------- GEMM2: wave w owns rows [16w,16w+16), all 64 cols --------
    f32x4 acc2[4];
#pragma unroll
    for (int ct = 0; ct < 4; ++ct) acc2[ct] = (f32x4)0.0f;

#pragma unroll
    for (int ks = 0; ks < 4; ++ks) {
        bf16x8 af = *reinterpret_cast<const bf16x8*>(
            &sA[(w * 16 + lr) * AS + ks * 32 + lq * 8]);
#pragma unroll
        for (int ct = 0; ct < 4; ++ct) {
            bf16x8 bf = *reinterpret_cast<const bf16x8*>(
                B2p + (size_t)((ks * 4 + ct) * 64 + lane) * 8);
            acc2[ct] = __builtin_amdgcn_mfma_f32_16x16x32_bf16(af, bf, acc2[ct], 0, 0, 0);
        }
    }

    // -------- GEMM3: relu(y+b2) . W3 + b3, fp32, 16-lane shfl reduce --------
    float w3v[4], b2v[4];
#pragma unroll
    for (int ct = 0; ct < 4; ++ct) {
        int c = ct * 16 + lr;
        w3v[ct] = W3[c];
        b2v[ct] = b2[c];
    }
#pragma unroll
    for (int r = 0; r < 4; ++r) {
        float sum = 0.0f;
#pragma unroll
        for (int ct = 0; ct < 4; ++ct)
            sum += fmaxf(acc2[ct][r] + b2v[ct], 0.0f) * w3v[ct];
        sum += __shfl_xor(sum, 1);
        sum += __shfl_xor(sum, 2);
        sum += __shfl_xor(sum, 4);
        sum += __shfl_xor(sum, 8);
        int e = ebase + w * 16 + lq * 4 + r;
        if (lr == 0 && e < n_edges) out[e] = sum + b3[0];
    }
}

extern "C" void kernel_launch(void* const* d_in, const int* in_sizes, int n_in,
                              void* d_out, int out_size, void* d_ws, size_t ws_size,
                              hipStream_t stream) {
    const float* h_src     = (const float*)d_in[0];
    const float* h_dst     = (const float*)d_in[1];
    const int*   src_nodes = (const int*)d_in[2];
    const int*   dst_nodes = (const int*)d_in[3];
    const int*   etype     = (const int*)d_in[4];
    const float* W1        = (const float*)d_in[5];
    const float* b1        = (const float*)d_in[6];
    const float* bn_gamma  = (const float*)d_in[7];
    const float* bn_beta   = (const float*)d_in[8];
    const float* bn_mean   = (const float*)d_in[9];
    const float* bn_var    = (const float*)d_in[10];
    const float* emb       = (const float*)d_in[11];
    const float* W2        = (const float*)d_in[12];
    const float* b2        = (const float*)d_in[13];
    const float* W3        = (const float*)d_in[14];
    const float* b3        = (const float*)d_in[15];

    // d_ws layout: B1p[65536 u16] | B2p[8192 u16] | sc[128 f32] | sh[128 f32]
    ushort* B1p = (ushort*)d_ws;
    ushort* B2p = B1p + 65536;
    float*  scp = (float*)(B2p + 8192);
    float*  shp = scp + HID;

    prep_kernel<<<(65536 + 8192 + HID + 255) / 256, 256, 0, stream>>>(
        W1, W2, bn_gamma, bn_beta, bn_mean, bn_var, emb, etype, B1p, B2p, scp, shp);

    const int n_edges = in_sizes[2];
    const int grid = (n_edges + ETILE - 1) / ETILE;
    edge_mlp_mfma<<<grid, 256, 0, stream>>>(h_src, h_dst, src_nodes, dst_nodes,
                                            B1p, B2p, b1, scp, shp, b2, W3, b3,
                                            (float*)d_out, n_edges);
}

// Round 6
// 102.873 us; speedup vs baseline: 5.5200x; 1.0066x over previous
//
#include <hip/hip_runtime.h>
#include <hip/hip_bf16.h>

// MultiEdgeTypePredictor — bf16 MFMA, software-pipelined gather (R3; third
// resubmit — three consecutive UnresponsiveContainer infra failures, source
// identical to the last benched-able round).
//
// prep_kernel: pack W1 (512x128) / W2 (128x64) into MFMA B-fragment layout
//              (bf16) in d_ws; fold BN+emb into per-column sc/sh.
// edge_mlp_mfma: 64-edge tile, 256 thr = 4 waves.
//   GEMM1: 8 K-chunks of 64, LDS double-buffered, issue-early/write-late
//          pipeline (gather latency hidden under MFMA of previous chunk).
//   GEMM2 + GEMM3 as before.

typedef __attribute__((ext_vector_type(8))) short bf16x8;
typedef __attribute__((ext_vector_type(4))) float f32x4;

constexpr int HID   = 128;
constexpr int ETILE = 64;
constexpr int AS    = 72;    // chunk-buffer row stride, bf16 elems (144 B)
constexpr int XS    = 136;   // x-tile row stride, bf16 elems (272 B)

__device__ inline ushort f2bf(float f) {
    union { __hip_bfloat16 h; ushort u; } cv;
    cv.h = __float2bfloat16(f);   // RNE
    return cv.u;
}

// ---------------- prep: pack weights + fold BN/emb ----------------
__global__ __launch_bounds__(256)
void prep_kernel(const float* __restrict__ W1, const float* __restrict__ W2,
                 const float* __restrict__ bn_gamma, const float* __restrict__ bn_beta,
                 const float* __restrict__ bn_mean, const float* __restrict__ bn_var,
                 const float* __restrict__ emb, const int* __restrict__ etype,
                 ushort* __restrict__ B1p, ushort* __restrict__ B2p,
                 float* __restrict__ sc, float* __restrict__ sh)
{
    int i = blockIdx.x * blockDim.x + threadIdx.x;
    if (i < 65536) {
        // B1 frag: i = ((ks*8 + ct)*64 + lane)*8 + j ; k = ks*32+(lane>>4)*8+j ; c = ct*16+(lane&15)
        int j = i & 7, lane = (i >> 3) & 63, ct = (i >> 9) & 7, ks = i >> 12;
        int k = ks * 32 + (lane >> 4) * 8 + j;
        int c = ct * 16 + (lane & 15);
        B1p[i] = f2bf(W1[k * HID + c]);
    } else if (i < 65536 + 8192) {
        int p = i - 65536;
        int j = p & 7, lane = (p >> 3) & 63, ct = (p >> 9) & 3, ks = p >> 11;
        int k = ks * 32 + (lane >> 4) * 8 + j;
        int c = ct * 16 + (lane & 15);
        B2p[p] = f2bf(W2[k * 64 + c]);
    } else if (i < 65536 + 8192 + HID) {
        int c = i - 65536 - 8192;
        float s = bn_gamma[c] * rsqrtf(bn_var[c] + 1e-5f);
        sc[c] = s;
        sh[c] = bn_beta[c] - bn_mean[c] * s + emb[etype[0] * HID + c];
    }
}

// ---------------- main fused kernel ----------------
__global__ __launch_bounds__(256, 4)
void edge_mlp_mfma(const float* __restrict__ h_src, const float* __restrict__ h_dst,
                   const int* __restrict__ src_nodes, const int* __restrict__ dst_nodes,
                   const ushort* __restrict__ B1p, const ushort* __restrict__ B2p,
                   const float* __restrict__ b1, const float* __restrict__ sc,
                   const float* __restrict__ sh, const float* __restrict__ b2,
                   const float* __restrict__ W3, const float* __restrict__ b3,
                   float* __restrict__ out, int n_edges)
{
    __shared__ ushort sA[2][ETILE * AS];     // 2 x 9216 B chunk buffers; later x-tile
    __shared__ int s_src[ETILE], s_dst[ETILE];

    const int t    = threadIdx.x;
    const int lane = t & 63;
    const int w    = t >> 6;          // wave 0..3
    const int lr   = lane & 15;
    const int lq   = lane >> 4;
    const int ebase = blockIdx.x * ETILE;

    if (t < ETILE) {
        int e = ebase + t;
        s_src[t] = src_nodes[e < n_edges ? e : 0];
    } else if (t < 2 * ETILE) {
        int e = ebase + t - ETILE;
        s_dst[t - ETILE] = dst_nodes[e < n_edges ? e : 0];
    }

    f32x4 acc[4][2];
#pragma unroll
    for (int rt = 0; rt < 4; ++rt)
#pragma unroll
        for (int c = 0; c < 2; ++c) acc[rt][c] = (f32x4)0.0f;

    float4 rA[4], rB[4];

    // chunk kc covers global k in [kc*64, kc*64+64): src for kc<4, dst for kc>=4
#define LOADC(kc, R) do {                                                      \
        const float* hp = ((kc) < 4) ? h_src : h_dst;                          \
        const int* sidx = ((kc) < 4) ? s_src : s_dst;                          \
        const int koff = ((kc) & 3) * 64;                                      \
        _Pragma("unroll")                                                      \
        for (int i = 0; i < 4; ++i) {                                          \
            int f = t + i * 256; int e = f >> 4; int q = f & 15;               \
            R[i] = *reinterpret_cast<const float4*>(                           \
                hp + (size_t)sidx[e] * 256 + koff + q * 4);                    \
        } } while (0)

#define STOREC(B, R) do {                                                      \
        _Pragma("unroll")                                                      \
        for (int i = 0; i < 4; ++i) {                                          \
            int f = t + i * 256; int e = f >> 4; int q = f & 15;               \
            ushort4 bv;                                                        \
            bv.x = f2bf(R[i].x); bv.y = f2bf(R[i].y);                          \
            bv.z = f2bf(R[i].z); bv.w = f2bf(R[i].w);                          \
            *reinterpret_cast<ushort4*>(&sA[B][e * AS + q * 4]) = bv;          \
        } } while (0)

#define COMP(kc, B) do {                                                       \
        _Pragma("unroll")                                                      \
        for (int ks = 0; ks < 2; ++ks) {                                       \
            const int kstep = (kc) * 2 + ks;                                   \
            bf16x8 bf0 = *reinterpret_cast<const bf16x8*>(                     \
                B1p + (size_t)(((kstep * 8) + 2 * w) * 64 + lane) * 8);        \
            bf16x8 bf1 = *reinterpret_cast<const bf16x8*>(                     \
                B1p + (size_t)(((kstep * 8) + 2 * w + 1) * 64 + lane) * 8);    \
            _Pragma("unroll")                                                  \
            for (int rt = 0; rt < 4; ++rt) {                                   \
                bf16x8 af = *reinterpret_cast<const bf16x8*>(                  \
                    &sA[B][(rt * 16 + lr) * AS + ks * 32 + lq * 8]);           \
                acc[rt][0] = __builtin_amdgcn_mfma_f32_16x16x32_bf16(af, bf0, acc[rt][0], 0, 0, 0); \
                acc[rt][1] = __builtin_amdgcn_mfma_f32_16x16x32_bf16(af, bf1, acc[rt][1], 0, 0, 0); \
            } } } while (0)

    __syncthreads();                 // indices ready
    LOADC(0, rA);
    STOREC(0, rA);
    LOADC(1, rB);
    __syncthreads();

    // steady state: issue gather kc+2, compute kc, write kc+1, barrier
    LOADC(2, rA);  COMP(0, 0);  STOREC(1, rB);  __syncthreads();
    LOADC(3, rB);  COMP(1, 1);  STOREC(0, rA);  __syncthreads();
    LOADC(4, rA);  COMP(2, 0);  STOREC(1, rB);  __syncthreads();
    LOADC(5, rB);  COMP(3, 1);  STOREC(0, rA);  __syncthreads();
    LOADC(6, rA);  COMP(4, 0);  STOREC(1, rB);  __syncthreads();
    LOADC(7, rB);  COMP(5, 1);  STOREC(0, rA);  __syncthreads();
                   COMP(6, 0);  STOREC(1, rB);  __syncthreads();
                   COMP(7, 1);

#undef LOADC
#undef STOREC
#undef COMP

    // -------- epilogue1: bias+relu+BN+emb -> x-tile (bf16, flat over sA) -----
    __syncthreads();                 // all COMP(7) readers done
    ushort* sX = &sA[0][0];          // 64 x XS(136) = 8704 ushorts <= 9216 avail
#pragma unroll
    for (int ctl = 0; ctl < 2; ++ctl) {
        int c = (2 * w + ctl) * 16 + lr;
        float bb = b1[c], s = sc[c], z = sh[c];
#pragma unroll
        for (int rt = 0; rt < 4; ++rt)
#pragma unroll
            for (int r = 0; r < 4; ++r) {
                float x = fmaxf(acc[rt][ctl][r] + bb, 0.0f);
                sX[(rt * 16 + lq * 4 + r) * XS + c] = f2bf(fmaf(x, s, z));
            }
    }
    __syncthreads();

    // -------- GEMM2: wave w owns rows [16w,16w+16), all 64 cols --------
    f32x4 acc2[4];
#pragma unroll
    for (int ct = 0; ct < 4; ++ct) acc2[ct] = (f32x4)0.0f;

#pragma unroll
    for (int ks = 0; ks < 4; ++ks) {
        bf16x8 af = *reinterpret_cast<const bf16x8*>(
            &sX[(w * 16 + lr) * XS + ks * 32 + lq * 8]);
#pragma unroll
        for (int ct = 0; ct < 4; ++ct) {
            bf16x8 bf = *reinterpret_cast<const bf16x8*>(
                B2p + (size_t)((ks * 4 + ct) * 64 + lane) * 8);
            acc2[ct] = __builtin_amdgcn_mfma_f32_16x16x32_bf16(af, bf, acc2[ct], 0, 0, 0);
        }
    }

    // -------- GEMM3: relu(y+b2) . W3 + b3, fp32, 16-lane shfl reduce --------
    float w3v[4], b2v[4];
#pragma unroll
    for (int ct = 0; ct < 4; ++ct) {
        int c = ct * 16 + lr;
        w3v[ct] = W3[c];
        b2v[ct] = b2[c];
    }
#pragma unroll
    for (int r = 0; r < 4; ++r) {
        float sum = 0.0f;
#pragma unroll
        for (int ct = 0; ct < 4; ++ct)
            sum += fmaxf(acc2[ct][r] + b2v[ct], 0.0f) * w3v[ct];
        sum += __shfl_xor(sum, 1);
        sum += __shfl_xor(sum, 2);
        sum += __shfl_xor(sum, 4);
        sum += __shfl_xor(sum, 8);
        int e = ebase + w * 16 + lq * 4 + r;
        if (lr == 0 && e < n_edges) out[e] = sum + b3[0];
    }
}

extern "C" void kernel_launch(void* const* d_in, const int* in_sizes, int n_in,
                              void* d_out, int out_size, void* d_ws, size_t ws_size,
                              hipStream_t stream) {
    const float* h_src     = (const float*)d_in[0];
    const float* h_dst     = (const float*)d_in[1];
    const int*   src_nodes = (const int*)d_in[2];
    const int*   dst_nodes = (const int*)d_in[3];
    const int*   etype     = (const int*)d_in[4];
    const float* W1        = (const float*)d_in[5];
    const float* b1        = (const float*)d_in[6];
    const float* bn_gamma  = (const float*)d_in[7];
    const float* bn_beta   = (const float*)d_in[8];
    const float* bn_mean   = (const float*)d_in[9];
    const float* bn_var    = (const float*)d_in[10];
    const float* emb       = (const float*)d_in[11];
    const float* W2        = (const float*)d_in[12];
    const float* b2        = (const float*)d_in[13];
    const float* W3        = (const float*)d_in[14];
    const float* b3        = (const float*)d_in[15];

    // d_ws layout: B1p[65536 u16] | B2p[8192 u16] | sc[128 f32] | sh[128 f32]
    ushort* B1p = (ushort*)d_ws;
    ushort* B2p = B1p + 65536;
    float*  scp = (float*)(B2p + 8192);
    float*  shp = scp + HID;

    prep_kernel<<<(65536 + 8192 + HID + 255) / 256, 256, 0, stream>>>(
        W1, W2, bn_gamma, bn_beta, bn_mean, bn_var, emb, etype, B1p, B2p, scp, shp);

    const int n_edges = in_sizes[2];
    const int grid = (n_edges + ETILE - 1) / ETILE;
    edge_mlp_mfma<<<grid, 256, 0, stream>>>(h_src, h_dst, src_nodes, dst_nodes,
                                            B1p, B2p, b1, scp, shp, b2, W3, b3,
                                            (float*)d_out, n_edges);
}

// Round 7
// 97.021 us; speedup vs baseline: 5.8530x; 1.0603x over previous
//
#include <hip/hip_runtime.h>
#include <hip/hip_bf16.h>

// MultiEdgeTypePredictor — bf16 MFMA, counted-barrier pipeline (R4).
//
// Key change vs R3: the GEMM1 K-loop uses raw s_barrier with lgkmcnt(0) only
// (NO vmcnt drain) so prefetched gathers stay in flight across barriers
// (R3's __syncthreads() compiled to vmcnt(0) -> zero latency hiding).
// B1 fragments are double-buffered in registers, loaded 2 phases ahead,
// so the compute phase is pure ds_read + MFMA.

typedef __attribute__((ext_vector_type(8))) short bf16x8;
typedef __attribute__((ext_vector_type(4))) float f32x4;

constexpr int HID   = 128;
constexpr int ETILE = 64;
constexpr int AS    = 72;    // chunk-buffer row stride, bf16 elems (144 B)
constexpr int XS    = 136;   // x-tile row stride, bf16 elems (272 B)

__device__ inline ushort f2bf(float f) {
    union { __hip_bfloat16 h; ushort u; } cv;
    cv.h = __float2bfloat16(f);   // RNE
    return cv.u;
}

// ---------------- prep: pack weights + fold BN/emb ----------------
__global__ __launch_bounds__(256)
void prep_kernel(const float* __restrict__ W1, const float* __restrict__ W2,
                 const float* __restrict__ bn_gamma, const float* __restrict__ bn_beta,
                 const float* __restrict__ bn_mean, const float* __restrict__ bn_var,
                 const float* __restrict__ emb, const int* __restrict__ etype,
                 ushort* __restrict__ B1p, ushort* __restrict__ B2p,
                 float* __restrict__ sc, float* __restrict__ sh)
{
    int i = blockIdx.x * blockDim.x + threadIdx.x;
    if (i < 65536) {
        // B1 frag: i = ((ks*8 + ct)*64 + lane)*8 + j ; k = ks*32+(lane>>4)*8+j ; c = ct*16+(lane&15)
        int j = i & 7, lane = (i >> 3) & 63, ct = (i >> 9) & 7, ks = i >> 12;
        int k = ks * 32 + (lane >> 4) * 8 + j;
        int c = ct * 16 + (lane & 15);
        B1p[i] = f2bf(W1[k * HID + c]);
    } else if (i < 65536 + 8192) {
        int p = i - 65536;
        int j = p & 7, lane = (p >> 3) & 63, ct = (p >> 9) & 3, ks = p >> 11;
        int k = ks * 32 + (lane >> 4) * 8 + j;
        int c = ct * 16 + (lane & 15);
        B2p[p] = f2bf(W2[k * 64 + c]);
    } else if (i < 65536 + 8192 + HID) {
        int c = i - 65536 - 8192;
        float s = bn_gamma[c] * rsqrtf(bn_var[c] + 1e-5f);
        sc[c] = s;
        sh[c] = bn_beta[c] - bn_mean[c] * s + emb[etype[0] * HID + c];
    }
}

// ---------------- main fused kernel ----------------
__global__ __launch_bounds__(256, 4)
void edge_mlp_mfma(const float* __restrict__ h_src, const float* __restrict__ h_dst,
                   const int* __restrict__ src_nodes, const int* __restrict__ dst_nodes,
                   const ushort* __restrict__ B1p, const ushort* __restrict__ B2p,
                   const float* __restrict__ b1, const float* __restrict__ sc,
                   const float* __restrict__ sh, const float* __restrict__ b2,
                   const float* __restrict__ W3, const float* __restrict__ b3,
                   float* __restrict__ out, int n_edges)
{
    __shared__ ushort sA[2][ETILE * AS];     // 2 x 9216 B chunk buffers; later x-tile
    __shared__ int s_src[ETILE], s_dst[ETILE];

    const int t    = threadIdx.x;
    const int lane = t & 63;
    const int w    = t >> 6;          // wave 0..3
    const int lr   = lane & 15;
    const int lq   = lane >> 4;
    const int ebase = blockIdx.x * ETILE;

    if (t < ETILE) {
        int e = ebase + t;
        s_src[t] = src_nodes[e < n_edges ? e : 0];
    } else if (t < 2 * ETILE) {
        int e = ebase + t - ETILE;
        s_dst[t - ETILE] = dst_nodes[e < n_edges ? e : 0];
    }

    f32x4 acc[4][2];
#pragma unroll
    for (int rt = 0; rt < 4; ++rt)
#pragma unroll
        for (int c = 0; c < 2; ++c) acc[rt][c] = (f32x4)0.0f;

    float4 rA[4], rB[4];
    bf16x8 Bf0[4], Bf1[4];     // B1 fragment double-buffer: [ks][ct] flattened

    // barrier WITHOUT vmcnt drain: ds_writes visible, gathers stay in flight
#define PHASE_BAR() do {                                                       \
        asm volatile("s_waitcnt lgkmcnt(0)" ::: "memory");                     \
        __builtin_amdgcn_s_barrier();                                          \
    } while (0)

    // chunk kc covers global k in [kc*64, kc*64+64): src for kc<4, dst for kc>=4
#define LOADC(kc, R) do {                                                      \
        const float* hp = ((kc) < 4) ? h_src : h_dst;                          \
        const int* sidx = ((kc) < 4) ? s_src : s_dst;                          \
        const int koff = ((kc) & 3) * 64;                                      \
        _Pragma("unroll")                                                      \
        for (int i = 0; i < 4; ++i) {                                          \
            int f = t + i * 256; int e = f >> 4; int q = f & 15;               \
            R[i] = *reinterpret_cast<const float4*>(                           \
                hp + (size_t)sidx[e] * 256 + koff + q * 4);                    \
        } } while (0)

#define BLOAD(kc, BR) do {                                                     \
        _Pragma("unroll")                                                      \
        for (int s = 0; s < 2; ++s)                                            \
        _Pragma("unroll")                                                      \
        for (int c = 0; c < 2; ++c)                                            \
            BR[s * 2 + c] = *reinterpret_cast<const bf16x8*>(                  \
                B1p + (size_t)((((kc) * 2 + s) * 8 + 2 * w + c) * 64 + lane) * 8); \
        } while (0)

#define STOREC(B, R) do {                                                      \
        _Pragma("unroll")                                                      \
        for (int i = 0; i < 4; ++i) {                                          \
            int f = t + i * 256; int e = f >> 4; int q = f & 15;               \
            ushort4 bv;                                                        \
            bv.x = f2bf(R[i].x); bv.y = f2bf(R[i].y);                          \
            bv.z = f2bf(R[i].z); bv.w = f2bf(R[i].w);                          \
            *reinterpret_cast<ushort4*>(&sA[B][e * AS + q * 4]) = bv;          \
        } } while (0)

#define COMP(B, BR) do {                                                       \
        _Pragma("unroll")                                                      \
        for (int ks = 0; ks < 2; ++ks) {                                       \
            _Pragma("unroll")                                                  \
            for (int rt = 0; rt < 4; ++rt) {                                   \
                bf16x8 af = *reinterpret_cast<const bf16x8*>(                  \
                    &sA[B][(rt * 16 + lr) * AS + ks * 32 + lq * 8]);           \
                acc[rt][0] = __builtin_amdgcn_mfma_f32_16x16x32_bf16(af, BR[ks * 2 + 0], acc[rt][0], 0, 0, 0); \
                acc[rt][1] = __builtin_amdgcn_mfma_f32_16x16x32_bf16(af, BR[ks * 2 + 1], acc[rt][1], 0, 0, 0); \
            } } } while (0)

    __syncthreads();                 // indices ready (full sync OK: no prefetch yet)

    // prologue
    LOADC(0, rA);
    BLOAD(0, Bf0);
    STOREC(0, rA);                   // waits gathers(0): unavoidable startup cost
    LOADC(1, rB);
    BLOAD(1, Bf1);
    PHASE_BAR();                     // buf0 ready; gathers(1) still in flight

    // steady state: gathers get ~1.5 phases to land; barriers never drain vmcnt
    LOADC(2, rA);  COMP(0, Bf0);  BLOAD(2, Bf0);  STOREC(1, rB);  PHASE_BAR();
    LOADC(3, rB);  COMP(1, Bf1);  BLOAD(3, Bf1);  STOREC(0, rA);  PHASE_BAR();
    LOADC(4, rA);  COMP(0, Bf0);  BLOAD(4, Bf0);  STOREC(1, rB);  PHASE_BAR();
    LOADC(5, rB);  COMP(1, Bf1);  BLOAD(5, Bf1);  STOREC(0, rA);  PHASE_BAR();
    LOADC(6, rA);  COMP(0, Bf0);  BLOAD(6, Bf0);  STOREC(1, rB);  PHASE_BAR();
    LOADC(7, rB);  COMP(1, Bf1);  BLOAD(7, Bf1);  STOREC(0, rA);  PHASE_BAR();
                   COMP(0, Bf0);                  STOREC(1, rB);  PHASE_BAR();
                   COMP(1, Bf1);

#undef LOADC
#undef BLOAD
#undef STOREC
#undef COMP
#undef PHASE_BAR

    // -------- epilogue1: bias+relu+BN+emb -> x-tile (bf16, flat over sA) -----
    __syncthreads();                 // all COMP readers done (full drain fine here)
    ushort* sX = &sA[0][0];          // 64 x XS(136) = 8704 ushorts <= 9216 avail
#pragma unroll
    for (int ctl = 0; ctl < 2; ++ctl) {
        int c = (2 * w + ctl) * 16 + lr;
        float bb = b1[c], s = sc[c], z = sh[c];
#pragma unroll
        for (int rt = 0; rt < 4; ++rt)
#pragma unroll
            for (int r = 0; r < 4; ++r) {
                float x = fmaxf(acc[rt][ctl][r] + bb, 0.0f);
                sX[(rt * 16 + lq * 4 + r) * XS + c] = f2bf(fmaf(x, s, z));
            }
    }
    __syncthreads();

    // -------- GEMM2: wave w owns rows [16w,16w+16), all 64 cols --------
    f32x4 acc2[4];
#pragma unroll
    for (int ct = 0; ct < 4; ++ct) acc2[ct] = (f32x4)0.0f;

#pragma unroll
    for (int ks = 0; ks < 4; ++ks) {
        bf16x8 af = *reinterpret_cast<const bf16x8*>(
            &sX[(w * 16 + lr) * XS + ks * 32 + lq * 8]);
#pragma unroll
        for (int ct = 0; ct < 4; ++ct) {
            bf16x8 bf = *reinterpret_cast<const bf16x8*>(
                B2p + (size_t)((ks * 4 + ct) * 64 + lane) * 8);
            acc2[ct] = __builtin_amdgcn_mfma_f32_16x16x32_bf16(af, bf, acc2[ct], 0, 0, 0);
        }
    }

    // -------- GEMM3: relu(y+b2) . W3 + b3, fp32, 16-lane shfl reduce --------
    float w3v[4], b2v[4];
#pragma unroll
    for (int ct = 0; ct < 4; ++ct) {
        int c = ct * 16 + lr;
        w3v[ct] = W3[c];
        b2v[ct] = b2[c];
    }
#pragma unroll
    for (int r = 0; r < 4; ++r) {
        float sum = 0.0f;
#pragma unroll
        for (int ct = 0; ct < 4; ++ct)
            sum += fmaxf(acc2[ct][r] + b2v[ct], 0.0f) * w3v[ct];
        sum += __shfl_xor(sum, 1);
        sum += __shfl_xor(sum, 2);
        sum += __shfl_xor(sum, 4);
        sum += __shfl_xor(sum, 8);
        int e = ebase + w * 16 + lq * 4 + r;
        if (lr == 0 && e < n_edges) out[e] = sum + b3[0];
    }
}

extern "C" void kernel_launch(void* const* d_in, const int* in_sizes, int n_in,
                              void* d_out, int out_size, void* d_ws, size_t ws_size,
                              hipStream_t stream) {
    const float* h_src     = (const float*)d_in[0];
    const float* h_dst     = (const float*)d_in[1];
    const int*   src_nodes = (const int*)d_in[2];
    const int*   dst_nodes = (const int*)d_in[3];
    const int*   etype     = (const int*)d_in[4];
    const float* W1        = (const float*)d_in[5];
    const float* b1        = (const float*)d_in[6];
    const float* bn_gamma  = (const float*)d_in[7];
    const float* bn_beta   = (const float*)d_in[8];
    const float* bn_mean   = (const float*)d_in[9];
    const float* bn_var    = (const float*)d_in[10];
    const float* emb       = (const float*)d_in[11];
    const float* W2        = (const float*)d_in[12];
    const float* b2        = (const float*)d_in[13];
    const float* W3        = (const float*)d_in[14];
    const float* b3        = (const float*)d_in[15];

    // d_ws layout: B1p[65536 u16] | B2p[8192 u16] | sc[128 f32] | sh[128 f32]
    ushort* B1p = (ushort*)d_ws;
    ushort* B2p = B1p + 65536;
    float*  scp = (float*)(B2p + 8192);
    float*  shp = scp + HID;

    prep_kernel<<<(65536 + 8192 + HID + 255) / 256, 256, 0, stream>>>(
        W1, W2, bn_gamma, bn_beta, bn_mean, bn_var, emb, etype, B1p, B2p, scp, shp);

    const int n_edges = in_sizes[2];
    const int grid = (n_edges + ETILE - 1) / ETILE;
    edge_mlp_mfma<<<grid, 256, 0, stream>>>(h_src, h_dst, src_nodes, dst_nodes,
                                            B1p, B2p, b1, scp, shp, b2, W3, b3,
                                            (float*)d_out, n_edges);
}